// Round 2
// baseline (218.035 us; speedup 1.0000x reference)
//
#include <hip/hip_runtime.h>
#include <hip/hip_bf16.h>

typedef unsigned short ushortT;
typedef unsigned int uintT;

#define BATCH   2048
#define NELEC   64
#define BN_EPS  1e-5f

// ws layout (float offsets)
#define OFF_A      0                    // A matrix 64x64
#define OFF_AMEAN  4096                 // 64
#define OFF_SS1    4160                 // scale1[64], shift1[64]
#define OFF_SS2    4288                 // scale2[128], shift2[128]
#define OFF_PS1    4544                 // [64 slots][64] sums
#define OFF_PQ1    8640                 // [64][64] sumsq
#define OFF_PS2    12736                // [64][128]
#define OFF_PQ2    20928                // [64][128]
#define OFF_H1     29120                // h1 fp32: 2048*64*64
#define OFF_H2     (29120 + 8388608)    // h2 bf16 (ushort region): 2048*64*128

__device__ inline float bf2f(ushortT u) { return __uint_as_float(((uintT)u) << 16); }
__device__ inline ushortT f2bf(float f) {
  uintT u = __float_as_uint(f);
  u = (u + 0x7FFFu + ((u >> 16) & 1u)) >> 16;
  return (ushortT)u;
}

// ---------------- prep: build A (64x64), amean, zero stat slots ----------------
__global__ __launch_bounds__(256) void prep_kernel(const int* __restrict__ src,
                                                   const int* __restrict__ dst,
                                                   int E, float* __restrict__ ws) {
  __shared__ float degS[NELEC];
  __shared__ float As[NELEC * NELEC];
  int t = threadIdx.x;
  if (t < NELEC) degS[t] = 1.0f;               // self-loop
  for (int i = t; i < NELEC * NELEC; i += 256) As[i] = 0.0f;
  __syncthreads();
  for (int e = t; e < E; e += 256) atomicAdd(&degS[dst[e]], 1.0f);
  __syncthreads();
  for (int e = t; e < E; e += 256) {
    float en = rsqrtf(degS[src[e]]) * rsqrtf(degS[dst[e]]);
    atomicAdd(&As[dst[e] * NELEC + src[e]], en);
  }
  __syncthreads();
  if (t < NELEC) As[t * NELEC + t] += 1.0f / degS[t];
  __syncthreads();
  for (int i = t; i < NELEC * NELEC; i += 256) ws[OFF_A + i] = As[i];
  if (t < NELEC) {
    float s = 0.0f;
    for (int n = 0; n < NELEC; ++n) s += As[n * NELEC + t];
    ws[OFF_AMEAN + t] = s * (1.0f / NELEC);
  }
  for (int i = t; i < (OFF_H1 - OFF_PS1); i += 256) ws[OFF_PS1 + i] = 0.0f;
}

// ---------------- layer 1: h1 = A*(x@W1)+b1 ; partial BN stats ----------------
__global__ __launch_bounds__(256) void layer1_kernel(const float* __restrict__ x,
    const float* __restrict__ W1, const float* __restrict__ b1,
    float* __restrict__ ws) {
  __shared__ float Xs[64][68];    // x tile, then T = x@W1
  __shared__ float Wsh[64][68];   // W1, then sum scratch
  __shared__ float Ash[64][68];   // A, then sumsq scratch
  const int b = blockIdx.x;
  const int t = threadIdx.x;
  const int tn = t >> 4, to = t & 15;
  const int tn4 = tn * 4, to4 = to * 4;

  const float4* xb  = (const float4*)(x + (size_t)b * 4096);
  const float4* w1v = (const float4*)W1;
  const float4* av  = (const float4*)(ws + OFF_A);
  for (int i = t; i < 1024; i += 256) {
    int row = i >> 4, c = (i & 15) * 4;
    *(float4*)&Xs[row][c]  = xb[i];
    *(float4*)&Wsh[row][c] = w1v[i];
    *(float4*)&Ash[row][c] = av[i];
  }
  __syncthreads();

  // GEMM1: T[n][o] = sum_k x[n][k] * W1[k][o]
  float acc[4][4] = {};
  #pragma unroll 16
  for (int k = 0; k < 64; ++k) {
    float a[4];
    #pragma unroll
    for (int i = 0; i < 4; ++i) a[i] = Xs[tn4 + i][k];
    float4 bv = *(const float4*)&Wsh[k][to4];
    #pragma unroll
    for (int i = 0; i < 4; ++i) {
      acc[i][0] = fmaf(a[i], bv.x, acc[i][0]);
      acc[i][1] = fmaf(a[i], bv.y, acc[i][1]);
      acc[i][2] = fmaf(a[i], bv.z, acc[i][2]);
      acc[i][3] = fmaf(a[i], bv.w, acc[i][3]);
    }
  }
  __syncthreads();
  #pragma unroll
  for (int i = 0; i < 4; ++i)
    *(float4*)&Xs[tn4 + i][to4] = make_float4(acc[i][0], acc[i][1], acc[i][2], acc[i][3]);
  __syncthreads();

  // GEMM2: h[n][o] = sum_m A[n][m] * T[m][o]
  float h[4][4] = {};
  #pragma unroll 16
  for (int m = 0; m < 64; ++m) {
    float a[4];
    #pragma unroll
    for (int i = 0; i < 4; ++i) a[i] = Ash[tn4 + i][m];
    float4 bv = *(const float4*)&Xs[m][to4];
    #pragma unroll
    for (int i = 0; i < 4; ++i) {
      h[i][0] = fmaf(a[i], bv.x, h[i][0]);
      h[i][1] = fmaf(a[i], bv.y, h[i][1]);
      h[i][2] = fmaf(a[i], bv.z, h[i][2]);
      h[i][3] = fmaf(a[i], bv.w, h[i][3]);
    }
  }
  float4 bias = ((const float4*)b1)[to];
  float psum[4] = {}, psq[4] = {};
  float* h1p = ws + OFF_H1 + (size_t)b * 4096;
  #pragma unroll
  for (int i = 0; i < 4; ++i) {
    float4 hv;
    hv.x = h[i][0] + bias.x; hv.y = h[i][1] + bias.y;
    hv.z = h[i][2] + bias.z; hv.w = h[i][3] + bias.w;
    ((float4*)(h1p + (size_t)(tn4 + i) * 64))[to] = hv;
    psum[0] += hv.x; psq[0] += hv.x * hv.x;
    psum[1] += hv.y; psq[1] += hv.y * hv.y;
    psum[2] += hv.z; psq[2] += hv.z * hv.z;
    psum[3] += hv.w; psq[3] += hv.w * hv.w;
  }
  __syncthreads();   // all GEMM reads of Wsh/Ash done
  #pragma unroll
  for (int j = 0; j < 4; ++j) {
    Wsh[tn][to4 + j] = psum[j];
    Ash[tn][to4 + j] = psq[j];
  }
  __syncthreads();
  if (t < 64) {
    float S = 0.0f, Q = 0.0f;
    #pragma unroll
    for (int g = 0; g < 16; ++g) { S += Wsh[g][t]; Q += Ash[g][t]; }
    int slot = b & 63;
    atomicAdd(&ws[OFF_PS1 + slot * 64 + t], S);
    atomicAdd(&ws[OFF_PQ1 + slot * 64 + t], Q);
  }
}

// ---------------- BN finalize ----------------
__global__ void reduce1_kernel(const float* __restrict__ g1, const float* __restrict__ be1,
                               float* __restrict__ ws) {
  int t = threadIdx.x;
  if (t < 64) {
    float S = 0.0f, Q = 0.0f;
    for (int s = 0; s < 64; ++s) { S += ws[OFF_PS1 + s * 64 + t]; Q += ws[OFF_PQ1 + s * 64 + t]; }
    const float inv = 1.0f / (float)(BATCH * NELEC);
    float m = S * inv;
    float v = fmaxf(Q * inv - m * m, 0.0f);
    float sc = g1[t] * rsqrtf(v + BN_EPS);
    ws[OFF_SS1 + t] = sc;
    ws[OFF_SS1 + 64 + t] = fmaf(-m, sc, be1[t]);
  }
}

__global__ void reduce2_kernel(const float* __restrict__ g2, const float* __restrict__ be2,
                               float* __restrict__ ws) {
  int t = threadIdx.x;
  if (t < 128) {
    float S = 0.0f, Q = 0.0f;
    for (int s = 0; s < 64; ++s) { S += ws[OFF_PS2 + s * 128 + t]; Q += ws[OFF_PQ2 + s * 128 + t]; }
    const float inv = 1.0f / (float)(BATCH * NELEC);
    float m = S * inv;
    float v = fmaxf(Q * inv - m * m, 0.0f);
    float sc = g2[t] * rsqrtf(v + BN_EPS);
    ws[OFF_SS2 + t] = sc;
    ws[OFF_SS2 + 128 + t] = fmaf(-m, sc, be2[t]);
  }
}

// ---------------- layer 2: h2 = A*(relu(bn(h1))@W2)+b2 ; partial stats ----------------
__global__ __launch_bounds__(256) void layer2_kernel(const float* __restrict__ W2,
    const float* __restrict__ b2, float* __restrict__ ws) {
  __shared__ float Ys[64][68];     // y = relu(bn(h1)), then A, then stat scratch
  __shared__ float Wsh[64][132];   // W2, then T2
  const int b = blockIdx.x, t = threadIdx.x;
  const int tn = t >> 4, to = t & 15;
  const int tn4 = tn * 4, to8 = to * 8;

  const float4* h1v  = (const float4*)(ws + OFF_H1 + (size_t)b * 4096);
  const float4* s1v  = (const float4*)(ws + OFF_SS1);
  const float4* sh1v = (const float4*)(ws + OFF_SS1 + 64);
  for (int i = t; i < 1024; i += 256) {
    int c4 = i & 15;
    float4 v = h1v[i];
    float4 s = s1v[c4], sh = sh1v[c4];
    v.x = fmaxf(fmaf(v.x, s.x, sh.x), 0.0f);
    v.y = fmaxf(fmaf(v.y, s.y, sh.y), 0.0f);
    v.z = fmaxf(fmaf(v.z, s.z, sh.z), 0.0f);
    v.w = fmaxf(fmaf(v.w, s.w, sh.w), 0.0f);
    *(float4*)&Ys[i >> 4][c4 * 4] = v;
  }
  const float4* w2v = (const float4*)W2;
  for (int i = t; i < 2048; i += 256)
    *(float4*)&Wsh[i >> 5][(i & 31) * 4] = w2v[i];
  __syncthreads();

  // GEMM1: T2[n][o] = sum_k y[n][k]*W2[k][o]   (64x128, K=64)
  float acc[4][8] = {};
  #pragma unroll 8
  for (int k = 0; k < 64; ++k) {
    float a[4];
    #pragma unroll
    for (int i = 0; i < 4; ++i) a[i] = Ys[tn4 + i][k];
    float4 b0 = *(const float4*)&Wsh[k][to8];
    float4 b1v = *(const float4*)&Wsh[k][to8 + 4];
    #pragma unroll
    for (int i = 0; i < 4; ++i) {
      acc[i][0] = fmaf(a[i], b0.x, acc[i][0]);
      acc[i][1] = fmaf(a[i], b0.y, acc[i][1]);
      acc[i][2] = fmaf(a[i], b0.z, acc[i][2]);
      acc[i][3] = fmaf(a[i], b0.w, acc[i][3]);
      acc[i][4] = fmaf(a[i], b1v.x, acc[i][4]);
      acc[i][5] = fmaf(a[i], b1v.y, acc[i][5]);
      acc[i][6] = fmaf(a[i], b1v.z, acc[i][6]);
      acc[i][7] = fmaf(a[i], b1v.w, acc[i][7]);
    }
  }
  __syncthreads();
  #pragma unroll
  for (int i = 0; i < 4; ++i) {
    *(float4*)&Wsh[tn4 + i][to8]     = make_float4(acc[i][0], acc[i][1], acc[i][2], acc[i][3]);
    *(float4*)&Wsh[tn4 + i][to8 + 4] = make_float4(acc[i][4], acc[i][5], acc[i][6], acc[i][7]);
  }
  const float4* av = (const float4*)(ws + OFF_A);
  for (int i = t; i < 1024; i += 256)
    *(float4*)&Ys[i >> 4][(i & 15) * 4] = av[i];
  __syncthreads();

  // GEMM2: h[n][o] = sum_m A[n][m]*T2[m][o]
  float h[4][8] = {};
  #pragma unroll 8
  for (int m = 0; m < 64; ++m) {
    float a[4];
    #pragma unroll
    for (int i = 0; i < 4; ++i) a[i] = Ys[tn4 + i][m];
    float4 b0 = *(const float4*)&Wsh[m][to8];
    float4 b1v = *(const float4*)&Wsh[m][to8 + 4];
    #pragma unroll
    for (int i = 0; i < 4; ++i) {
      h[i][0] = fmaf(a[i], b0.x, h[i][0]);
      h[i][1] = fmaf(a[i], b0.y, h[i][1]);
      h[i][2] = fmaf(a[i], b0.z, h[i][2]);
      h[i][3] = fmaf(a[i], b0.w, h[i][3]);
      h[i][4] = fmaf(a[i], b1v.x, h[i][4]);
      h[i][5] = fmaf(a[i], b1v.y, h[i][5]);
      h[i][6] = fmaf(a[i], b1v.z, h[i][6]);
      h[i][7] = fmaf(a[i], b1v.w, h[i][7]);
    }
  }
  float4 bias0 = ((const float4*)b2)[to * 2];
  float4 bias1 = ((const float4*)b2)[to * 2 + 1];
  float psum[8] = {}, psq[8] = {};
  ushortT* h2p = (ushortT*)(ws + OFF_H2) + (size_t)b * 8192;
  #pragma unroll
  for (int i = 0; i < 4; ++i) {
    float v[8];
    v[0] = h[i][0] + bias0.x; v[1] = h[i][1] + bias0.y;
    v[2] = h[i][2] + bias0.z; v[3] = h[i][3] + bias0.w;
    v[4] = h[i][4] + bias1.x; v[5] = h[i][5] + bias1.y;
    v[6] = h[i][6] + bias1.z; v[7] = h[i][7] + bias1.w;
    uint4 pk;
    pk.x = (uintT)f2bf(v[0]) | ((uintT)f2bf(v[1]) << 16);
    pk.y = (uintT)f2bf(v[2]) | ((uintT)f2bf(v[3]) << 16);
    pk.z = (uintT)f2bf(v[4]) | ((uintT)f2bf(v[5]) << 16);
    pk.w = (uintT)f2bf(v[6]) | ((uintT)f2bf(v[7]) << 16);
    *(uint4*)(h2p + (size_t)(tn4 + i) * 128 + to8) = pk;
    #pragma unroll
    for (int j = 0; j < 8; ++j) { psum[j] += v[j]; psq[j] += v[j] * v[j]; }
  }
  __syncthreads();
  float* red = &Ys[0][0];   // 4352 floats available, need 4096
  #pragma unroll
  for (int j = 0; j < 8; ++j) {
    red[tn * 128 + to8 + j] = psum[j];
    red[2048 + tn * 128 + to8 + j] = psq[j];
  }
  __syncthreads();
  if (t < 128) {
    float S = 0.0f, Q = 0.0f;
    #pragma unroll
    for (int g = 0; g < 16; ++g) { S += red[g * 128 + t]; Q += red[2048 + g * 128 + t]; }
    int slot = b & 63;
    atomicAdd(&ws[OFF_PS2 + slot * 128 + t], S);
    atomicAdd(&ws[OFF_PQ2 + slot * 128 + t], Q);
  }
}

// ---------------- layer 3 (+ mean pool): out[b] = (amean@relu(bn2(h2[b])))@W3 + b3 ----------------
#define L3_ITEMS 4
__global__ __launch_bounds__(256) void layer3_kernel(const float* __restrict__ W3,
    const float* __restrict__ b3, const float* __restrict__ ws,
    float* __restrict__ out) {
  __shared__ float W3s[128][132];
  __shared__ float vS[2][128];
  __shared__ float oS[128];
  __shared__ float am[64];
  const int t = threadIdx.x;
  const int g = t >> 7, f = t & 127;
  const float4* w3v = (const float4*)W3;
  for (int i = t; i < 4096; i += 256)
    *(float4*)&W3s[i >> 5][(i & 31) * 4] = w3v[i];
  if (t < 64) am[t] = ws[OFF_AMEAN + t];
  float s2  = ws[OFF_SS2 + f];
  float sh2 = ws[OFF_SS2 + 128 + f];
  float b3f = b3[f];
  __syncthreads();
  const ushortT* h2base = (const ushortT*)(ws + OFF_H2);
  for (int it = 0; it < L3_ITEMS; ++it) {
    int b = blockIdx.x * L3_ITEMS + it;
    const ushortT* h2b = h2base + (size_t)b * 8192;
    float vp = 0.0f;
    #pragma unroll 8
    for (int m = g; m < 64; m += 2) {
      float hv = bf2f(h2b[m * 128 + f]);
      vp += am[m] * fmaxf(fmaf(hv, s2, sh2), 0.0f);
    }
    vS[g][f] = vp;
    __syncthreads();
    float acc = 0.0f;
    #pragma unroll 8
    for (int k = 0; k < 64; ++k) {
      int fk = (g << 6) + k;
      acc = fmaf(vS[0][fk] + vS[1][fk], W3s[fk][f], acc);
    }
    if (g == 0) oS[f] = acc;
    __syncthreads();
    if (g == 1) out[(size_t)b * 128 + f] = oS[f] + acc + b3f;
    __syncthreads();
  }
}

extern "C" void kernel_launch(void* const* d_in, const int* in_sizes, int n_in,
                              void* d_out, int out_size, void* d_ws, size_t ws_size,
                              hipStream_t stream) {
  const float* x   = (const float*)d_in[0];
  const float* W1  = (const float*)d_in[1];
  const float* b1  = (const float*)d_in[2];
  const float* W2  = (const float*)d_in[3];
  const float* b2  = (const float*)d_in[4];
  const float* W3  = (const float*)d_in[5];
  const float* b3  = (const float*)d_in[6];
  const float* g1  = (const float*)d_in[7];
  const float* be1 = (const float*)d_in[8];
  const float* g2  = (const float*)d_in[9];
  const float* be2 = (const float*)d_in[10];
  const int*   src = (const int*)d_in[11];
  const int*   dst = (const int*)d_in[12];
  const int E = in_sizes[11];
  float* ws  = (float*)d_ws;
  float* out = (float*)d_out;

  hipLaunchKernelGGL(prep_kernel,   dim3(1),              dim3(256), 0, stream, src, dst, E, ws);
  hipLaunchKernelGGL(layer1_kernel, dim3(BATCH),          dim3(256), 0, stream, x, W1, b1, ws);
  hipLaunchKernelGGL(reduce1_kernel,dim3(1),              dim3(64),  0, stream, g1, be1, ws);
  hipLaunchKernelGGL(layer2_kernel, dim3(BATCH),          dim3(256), 0, stream, W2, b2, ws);
  hipLaunchKernelGGL(reduce2_kernel,dim3(1),              dim3(128), 0, stream, g2, be2, ws);
  hipLaunchKernelGGL(layer3_kernel, dim3(BATCH/L3_ITEMS), dim3(256), 0, stream, W3, b3, ws, out);
}

// Round 3
// 200.852 us; speedup vs baseline: 1.0855x; 1.0855x over previous
//
#include <hip/hip_runtime.h>
#include <hip/hip_bf16.h>

typedef unsigned short ushortT;
typedef unsigned int uintT;
typedef __attribute__((ext_vector_type(8))) short short8;
typedef __attribute__((ext_vector_type(4))) float f32x4;

#define BATCH   2048
#define NELEC   64
#define BN_EPS  1e-5f

// ws layout (float offsets)
#define OFF_AMEAN  4096                 // 64
#define OFF_SS1    4160                 // scale1[64], shift1[64]
#define OFF_SS2    4288                 // scale2[128], shift2[128]
#define OFF_PS1    4544                 // [64 slots][64] sums
#define OFF_PQ1    8640                 // [64][64] sumsq
#define OFF_PS2    12736                // [64][128]
#define OFF_PQ2    20928                // [64][128]  (ends 29120)
#define OFF_ABF    29120                // ushort: A_hi[4096], A_lo[4096]
#define OFF_W1T    33216                // ushort: W1t_hi[4096], W1t_lo[4096]  (W1t[o][k])
#define OFF_W2T    37312                // ushort: W2t_hi[8192], W2t_lo[8192]  (W2t[o][k])
#define OFF_H1     45504                // ushort h1[2048][64][64] bf16
#define OFF_H2     4239808              // ushort h2[2048][64][128] bf16

#define MFMA(a, b, c) __builtin_amdgcn_mfma_f32_16x16x32_bf16(a, b, c, 0, 0, 0)

__device__ inline float bf2f(ushortT u) { return __uint_as_float(((uintT)u) << 16); }
__device__ inline ushortT f2bf(float f) {
  uintT u = __float_as_uint(f);
  u = (u + 0x7FFFu + ((u >> 16) & 1u)) >> 16;
  return (ushortT)u;
}
__device__ inline void split2(float f, ushortT& hi, ushortT& lo) {
  hi = f2bf(f);
  lo = f2bf(f - bf2f(hi));
}
__device__ inline void split8(const float* f, short8& hi, short8& lo) {
  #pragma unroll
  for (int e = 0; e < 8; ++e) {
    ushortT h, l;
    split2(f[e], h, l);
    hi[e] = (short)h; lo[e] = (short)l;
  }
}

// ---------------- prep: build A (bf16 hi/lo), amean, W1t/W2t hi/lo ----------------
__global__ __launch_bounds__(256) void prep_kernel(const int* __restrict__ src,
    const int* __restrict__ dst, int E,
    const float* __restrict__ W1, const float* __restrict__ W2,
    float* __restrict__ ws) {
  __shared__ float degS[NELEC];
  __shared__ float As[NELEC * NELEC];
  int t = threadIdx.x;
  if (t < NELEC) degS[t] = 1.0f;               // self-loop
  for (int i = t; i < NELEC * NELEC; i += 256) As[i] = 0.0f;
  __syncthreads();
  for (int e = t; e < E; e += 256) atomicAdd(&degS[dst[e]], 1.0f);
  __syncthreads();
  for (int e = t; e < E; e += 256) {
    float en = rsqrtf(degS[src[e]]) * rsqrtf(degS[dst[e]]);
    atomicAdd(&As[dst[e] * NELEC + src[e]], en);
  }
  __syncthreads();
  if (t < NELEC) As[t * NELEC + t] += 1.0f / degS[t];
  __syncthreads();
  ushortT* abf = (ushortT*)(ws + OFF_ABF);
  for (int i = t; i < 4096; i += 256) {
    ushortT hi, lo; split2(As[i], hi, lo);
    abf[i] = hi; abf[4096 + i] = lo;
  }
  if (t < NELEC) {
    float s = 0.0f;
    for (int n = 0; n < NELEC; ++n) s += As[n * NELEC + t];
    ws[OFF_AMEAN + t] = s * (1.0f / NELEC);
  }
  ushortT* w1t = (ushortT*)(ws + OFF_W1T);
  for (int i = t; i < 4096; i += 256) {
    int o = i >> 6, k = i & 63;
    ushortT hi, lo; split2(W1[k * 64 + o], hi, lo);
    w1t[i] = hi; w1t[4096 + i] = lo;
  }
  ushortT* w2t = (ushortT*)(ws + OFF_W2T);
  for (int i = t; i < 8192; i += 256) {
    int o = i >> 6, k = i & 63;
    ushortT hi, lo; split2(W2[k * 128 + o], hi, lo);
    w2t[i] = hi; w2t[8192 + i] = lo;
  }
}

// ---------------- layer 1: h1 = A*(x@W1)+b1 (MFMA, wave-per-item) ----------------
__global__ __launch_bounds__(256) void layer1_mfma(const float* __restrict__ x,
    const float* __restrict__ b1, float* __restrict__ ws) {
  __shared__ ushortT TsH[4][16 * 72];   // per-wave strip bounce, padded stride 72
  __shared__ ushortT TsL[4][16 * 72];
  const int w = threadIdx.x >> 6, lane = threadIdx.x & 63;
  const int item = blockIdx.x * 4 + w;
  const int c = lane & 15, g = lane >> 4;
  const ushortT* abf = (const ushortT*)(ws + OFF_ABF);
  const ushortT* w1t = (const ushortT*)(ws + OFF_W1T);
  ushortT* h1p = (ushortT*)(ws + OFF_H1) + (size_t)item * 4096;
  ushortT* tsh = &TsH[w][0];
  ushortT* tsl = &TsL[w][0];

  // X fragments (A-operand of GEMM1), hi/lo split, persist
  short8 Xhi[4][2], Xlo[4][2];
  #pragma unroll
  for (int rt = 0; rt < 4; ++rt) {
    #pragma unroll
    for (int ks = 0; ks < 2; ++ks) {
      const float* p = x + (size_t)item * 4096 + (rt * 16 + c) * 64 + ks * 32 + g * 8;
      float4 fa = *(const float4*)p;
      float4 fb = *(const float4*)(p + 4);
      float f[8] = {fa.x, fa.y, fa.z, fa.w, fb.x, fb.y, fb.z, fb.w};
      split8(f, Xhi[rt][ks], Xlo[rt][ks]);
    }
  }

  for (int s = 0; s < 4; ++s) {
    // GEMM1 strip: T[:, s*16..] = X @ W1[:, strip]
    f32x4 t[4] = {{0,0,0,0},{0,0,0,0},{0,0,0,0},{0,0,0,0}};
    #pragma unroll
    for (int ks = 0; ks < 2; ++ks) {
      short8 bh = *(const short8*)(w1t + (s * 16 + c) * 64 + ks * 32 + g * 8);
      short8 bl = *(const short8*)(w1t + 4096 + (s * 16 + c) * 64 + ks * 32 + g * 8);
      #pragma unroll
      for (int rt = 0; rt < 4; ++rt) {
        t[rt] = MFMA(Xhi[rt][ks], bh, t[rt]);
        t[rt] = MFMA(Xhi[rt][ks], bl, t[rt]);
        t[rt] = MFMA(Xlo[rt][ks], bh, t[rt]);
      }
    }
    // bounce strip to LDS transposed: Ts[c][m], hi/lo
    #pragma unroll
    for (int rt = 0; rt < 4; ++rt) {
      ushortT h0, h1_, h2_, h3, l0, l1, l2, l3;
      split2(t[rt][0], h0, l0); split2(t[rt][1], h1_, l1);
      split2(t[rt][2], h2_, l2); split2(t[rt][3], h3, l3);
      uint2 wh, wl;
      wh.x = (uintT)h0 | ((uintT)h1_ << 16); wh.y = (uintT)h2_ | ((uintT)h3 << 16);
      wl.x = (uintT)l0 | ((uintT)l1 << 16);  wl.y = (uintT)l2 | ((uintT)l3 << 16);
      int idx = c * 72 + rt * 16 + g * 4;
      *(uint2*)(tsh + idx) = wh;
      *(uint2*)(tsl + idx) = wl;
    }
    // GEMM2 strip: h[:, strip] = A @ T-strip
    f32x4 hacc[4] = {{0,0,0,0},{0,0,0,0},{0,0,0,0},{0,0,0,0}};
    #pragma unroll
    for (int ks = 0; ks < 2; ++ks) {
      short8 th = *(const short8*)(tsh + c * 72 + ks * 32 + g * 8);
      short8 tl = *(const short8*)(tsl + c * 72 + ks * 32 + g * 8);
      #pragma unroll
      for (int rt = 0; rt < 4; ++rt) {
        short8 ah = *(const short8*)(abf + (rt * 16 + c) * 64 + ks * 32 + g * 8);
        short8 al = *(const short8*)(abf + 4096 + (rt * 16 + c) * 64 + ks * 32 + g * 8);
        hacc[rt] = MFMA(ah, th, hacc[rt]);
        hacc[rt] = MFMA(ah, tl, hacc[rt]);
        hacc[rt] = MFMA(al, th, hacc[rt]);
      }
    }
    // epilogue: +bias, stats, bf16 store (row-major h1[n][o])
    float bias = b1[s * 16 + c];
    float S = 0.0f, Q = 0.0f;
    #pragma unroll
    for (int rt = 0; rt < 4; ++rt) {
      #pragma unroll
      for (int r = 0; r < 4; ++r) {
        float v = hacc[rt][r] + bias;
        S += v; Q += v * v;
        h1p[(rt * 16 + g * 4 + r) * 64 + s * 16 + c] = f2bf(v);
      }
    }
    S += __shfl_xor(S, 16); S += __shfl_xor(S, 32);
    Q += __shfl_xor(Q, 16); Q += __shfl_xor(Q, 32);
    if (g == 0) {
      int slot = item & 63;
      atomicAdd(&ws[OFF_PS1 + slot * 64 + s * 16 + c], S);
      atomicAdd(&ws[OFF_PQ1 + slot * 64 + s * 16 + c], Q);
    }
  }
}

// ---------------- BN finalize ----------------
__global__ void reduce1_kernel(const float* __restrict__ g1, const float* __restrict__ be1,
                               float* __restrict__ ws) {
  int t = threadIdx.x;
  if (t < 64) {
    float S = 0.0f, Q = 0.0f;
    for (int s = 0; s < 64; ++s) { S += ws[OFF_PS1 + s * 64 + t]; Q += ws[OFF_PQ1 + s * 64 + t]; }
    const float inv = 1.0f / (float)(BATCH * NELEC);
    float m = S * inv;
    float v = fmaxf(Q * inv - m * m, 0.0f);
    float sc = g1[t] * rsqrtf(v + BN_EPS);
    ws[OFF_SS1 + t] = sc;
    ws[OFF_SS1 + 64 + t] = fmaf(-m, sc, be1[t]);
  }
}

__global__ void reduce2_kernel(const float* __restrict__ g2, const float* __restrict__ be2,
                               float* __restrict__ ws) {
  int t = threadIdx.x;
  if (t < 128) {
    float S = 0.0f, Q = 0.0f;
    for (int s = 0; s < 64; ++s) { S += ws[OFF_PS2 + s * 128 + t]; Q += ws[OFF_PQ2 + s * 128 + t]; }
    const float inv = 1.0f / (float)(BATCH * NELEC);
    float m = S * inv;
    float v = fmaxf(Q * inv - m * m, 0.0f);
    float sc = g2[t] * rsqrtf(v + BN_EPS);
    ws[OFF_SS2 + t] = sc;
    ws[OFF_SS2 + 128 + t] = fmaf(-m, sc, be2[t]);
  }
}

// ---------------- layer 2: h2 = A*(relu(bn(h1))@W2)+b2 (MFMA, wave-per-item) ----------------
__global__ __launch_bounds__(256) void layer2_mfma(const float* __restrict__ b2,
    float* __restrict__ ws) {
  __shared__ ushortT TsH[4][16 * 72];
  __shared__ ushortT TsL[4][16 * 72];
  const int w = threadIdx.x >> 6, lane = threadIdx.x & 63;
  const int item = blockIdx.x * 4 + w;
  const int c = lane & 15, g = lane >> 4;
  const ushortT* abf = (const ushortT*)(ws + OFF_ABF);
  const ushortT* w2t = (const ushortT*)(ws + OFF_W2T);
  const ushortT* h1p = (const ushortT*)(ws + OFF_H1) + (size_t)item * 4096;
  ushortT* h2p = (ushortT*)(ws + OFF_H2) + (size_t)item * 8192;
  ushortT* tsh = &TsH[w][0];
  ushortT* tsl = &TsL[w][0];

  // Y = relu(bn(h1)) fragments (A-operand), hi/lo split, persist
  short8 Yhi[4][2], Ylo[4][2];
  #pragma unroll
  for (int ks = 0; ks < 2; ++ks) {
    const float* sp = ws + OFF_SS1 + ks * 32 + g * 8;
    const float* tp = ws + OFF_SS1 + 64 + ks * 32 + g * 8;
    float4 sa = *(const float4*)sp, sb = *(const float4*)(sp + 4);
    float4 ta = *(const float4*)tp, tb = *(const float4*)(tp + 4);
    float s8[8] = {sa.x, sa.y, sa.z, sa.w, sb.x, sb.y, sb.z, sb.w};
    float t8[8] = {ta.x, ta.y, ta.z, ta.w, tb.x, tb.y, tb.z, tb.w};
    #pragma unroll
    for (int rt = 0; rt < 4; ++rt) {
      short8 hv = *(const short8*)(h1p + (rt * 16 + c) * 64 + ks * 32 + g * 8);
      float f[8];
      #pragma unroll
      for (int e = 0; e < 8; ++e)
        f[e] = fmaxf(fmaf(bf2f((ushortT)hv[e]), s8[e], t8[e]), 0.0f);
      split8(f, Yhi[rt][ks], Ylo[rt][ks]);
    }
  }

  for (int s = 0; s < 8; ++s) {
    // GEMM1 strip: T2[:, strip] = Y @ W2[:, strip]
    f32x4 t[4] = {{0,0,0,0},{0,0,0,0},{0,0,0,0},{0,0,0,0}};
    #pragma unroll
    for (int ks = 0; ks < 2; ++ks) {
      short8 bh = *(const short8*)(w2t + (s * 16 + c) * 64 + ks * 32 + g * 8);
      short8 bl = *(const short8*)(w2t + 8192 + (s * 16 + c) * 64 + ks * 32 + g * 8);
      #pragma unroll
      for (int rt = 0; rt < 4; ++rt) {
        t[rt] = MFMA(Yhi[rt][ks], bh, t[rt]);
        t[rt] = MFMA(Yhi[rt][ks], bl, t[rt]);
        t[rt] = MFMA(Ylo[rt][ks], bh, t[rt]);
      }
    }
    #pragma unroll
    for (int rt = 0; rt < 4; ++rt) {
      ushortT h0, h1_, h2_, h3, l0, l1, l2, l3;
      split2(t[rt][0], h0, l0); split2(t[rt][1], h1_, l1);
      split2(t[rt][2], h2_, l2); split2(t[rt][3], h3, l3);
      uint2 wh, wl;
      wh.x = (uintT)h0 | ((uintT)h1_ << 16); wh.y = (uintT)h2_ | ((uintT)h3 << 16);
      wl.x = (uintT)l0 | ((uintT)l1 << 16);  wl.y = (uintT)l2 | ((uintT)l3 << 16);
      int idx = c * 72 + rt * 16 + g * 4;
      *(uint2*)(tsh + idx) = wh;
      *(uint2*)(tsl + idx) = wl;
    }
    // GEMM2 strip: h2[:, strip] = A @ T2-strip
    f32x4 hacc[4] = {{0,0,0,0},{0,0,0,0},{0,0,0,0},{0,0,0,0}};
    #pragma unroll
    for (int ks = 0; ks < 2; ++ks) {
      short8 th = *(const short8*)(tsh + c * 72 + ks * 32 + g * 8);
      short8 tl = *(const short8*)(tsl + c * 72 + ks * 32 + g * 8);
      #pragma unroll
      for (int rt = 0; rt < 4; ++rt) {
        short8 ah = *(const short8*)(abf + (rt * 16 + c) * 64 + ks * 32 + g * 8);
        short8 al = *(const short8*)(abf + 4096 + (rt * 16 + c) * 64 + ks * 32 + g * 8);
        hacc[rt] = MFMA(ah, th, hacc[rt]);
        hacc[rt] = MFMA(ah, tl, hacc[rt]);
        hacc[rt] = MFMA(al, th, hacc[rt]);
      }
    }
    float bias = b2[s * 16 + c];
    float S = 0.0f, Q = 0.0f;
    #pragma unroll
    for (int rt = 0; rt < 4; ++rt) {
      #pragma unroll
      for (int r = 0; r < 4; ++r) {
        float v = hacc[rt][r] + bias;
        S += v; Q += v * v;
        h2p[(rt * 16 + g * 4 + r) * 128 + s * 16 + c] = f2bf(v);
      }
    }
    S += __shfl_xor(S, 16); S += __shfl_xor(S, 32);
    Q += __shfl_xor(Q, 16); Q += __shfl_xor(Q, 32);
    if (g == 0) {
      int slot = item & 63;
      atomicAdd(&ws[OFF_PS2 + slot * 128 + s * 16 + c], S);
      atomicAdd(&ws[OFF_PQ2 + slot * 128 + s * 16 + c], Q);
    }
  }
}

// ---------------- layer 3 (+ mean pool): out[b] = (amean@relu(bn2(h2[b])))@W3 + b3 ----------------
__global__ __launch_bounds__(256) void layer3_kernel(const float* __restrict__ W3,
    const float* __restrict__ b3, const float* __restrict__ ws,
    float* __restrict__ out) {
  const int w = threadIdx.x >> 6, lane = threadIdx.x & 63;
  const int item = blockIdx.x * 4 + w;
  const int f0 = lane * 2;
  const float s2a = ws[OFF_SS2 + f0],       s2b = ws[OFF_SS2 + f0 + 1];
  const float t2a = ws[OFF_SS2 + 128 + f0], t2b = ws[OFF_SS2 + 128 + f0 + 1];
  const float* am = ws + OFF_AMEAN;
  const ushortT* h2 = (const ushortT*)(ws + OFF_H2) + (size_t)item * 8192;
  float v0 = 0.0f, v1 = 0.0f;
  #pragma unroll 8
  for (int m = 0; m < 64; ++m) {
    uintT pk = *(const uintT*)(h2 + m * 128 + f0);
    float y0 = fmaxf(fmaf(bf2f((ushortT)(pk & 0xffffu)), s2a, t2a), 0.0f);
    float y1 = fmaxf(fmaf(bf2f((ushortT)(pk >> 16)),     s2b, t2b), 0.0f);
    float a = am[m];
    v0 = fmaf(a, y0, v0);
    v1 = fmaf(a, y1, v1);
  }
  float o0 = b3[f0], o1 = b3[f0 + 1];
  #pragma unroll 8
  for (int k = 0; k < 128; ++k) {
    float vk = __shfl((k & 1) ? v1 : v0, k >> 1, 64);
    o0 = fmaf(vk, W3[k * 128 + f0],     o0);
    o1 = fmaf(vk, W3[k * 128 + f0 + 1], o1);
  }
  float2 ov; ov.x = o0; ov.y = o1;
  *(float2*)(out + (size_t)item * 128 + f0) = ov;
}

extern "C" void kernel_launch(void* const* d_in, const int* in_sizes, int n_in,
                              void* d_out, int out_size, void* d_ws, size_t ws_size,
                              hipStream_t stream) {
  const float* x   = (const float*)d_in[0];
  const float* W1  = (const float*)d_in[1];
  const float* b1  = (const float*)d_in[2];
  const float* W2  = (const float*)d_in[3];
  const float* b2  = (const float*)d_in[4];
  const float* W3  = (const float*)d_in[5];
  const float* b3  = (const float*)d_in[6];
  const float* g1  = (const float*)d_in[7];
  const float* be1 = (const float*)d_in[8];
  const float* g2  = (const float*)d_in[9];
  const float* be2 = (const float*)d_in[10];
  const int*   src = (const int*)d_in[11];
  const int*   dst = (const int*)d_in[12];
  const int E = in_sizes[11];
  float* ws  = (float*)d_ws;
  float* out = (float*)d_out;

  // zero BN partial-stat slots (PS1..PQ2)
  hipMemsetAsync((void*)(ws + OFF_PS1), 0, (size_t)(29120 - OFF_PS1) * 4, stream);
  hipLaunchKernelGGL(prep_kernel,   dim3(1),   dim3(256), 0, stream, src, dst, E, W1, W2, ws);
  hipLaunchKernelGGL(layer1_mfma,   dim3(512), dim3(256), 0, stream, x, b1, ws);
  hipLaunchKernelGGL(reduce1_kernel,dim3(1),   dim3(64),  0, stream, g1, be1, ws);
  hipLaunchKernelGGL(layer2_mfma,   dim3(512), dim3(256), 0, stream, b2, ws);
  hipLaunchKernelGGL(reduce2_kernel,dim3(1),   dim3(128), 0, stream, g2, be2, ws);
  hipLaunchKernelGGL(layer3_kernel, dim3(512), dim3(256), 0, stream, W3, b3, ws, out);
}